// Round 1
// baseline (87.001 us; speedup 1.0000x reference)
//
#include <hip/hip_runtime.h>
#include <math.h>

#define BS   16
#define NQ   128
#define NCLS 3
#define T    480
#define P    72
#define BN   (BS * NQ)      // 2048
#define TROW (5 + 2 * P)    // 149
#define PT   (P * T)        // 34560
#define BNB  4              // bn per block in main kernel

// ws layout (floats):
//   lamT [P][T] at 0
//   txT  [P][T] at PT
//   tyT  [P][T] at 2*PT
//   w    [T]    at 3*PT
// total = 3*34560 + 480 = 104160 floats (~417 KB)

__global__ __launch_bounds__(256) void prep1_kernel(const float* __restrict__ targets,
                                                    float* __restrict__ ws) {
    int idx = blockIdx.x * 256 + threadIdx.x;   // exactly covers P*T = 34560
    int t = idx / P;
    int p = idx - t * P;
    const float* row = targets + t * TROW;
    float ly = row[1], uy = row[2], lx = row[3], ux = row[4];
    float tx = row[5 + p];
    float ty = row[5 + P + p];
    float dx = ux - lx, dy = uy - ly;
    float nrm = sqrtf(dx * dx + dy * dy);
    float dot = dx * (tx - lx) + dy * (ty - ly);
    float lam = dot / nrm / nrm;                // matches reference: dot/nrm/nrm
    ws[0 * PT + p * T + t] = lam;
    ws[1 * PT + p * T + t] = tx;
    ws[2 * PT + p * T + t] = ty;
}

__global__ __launch_bounds__(512) void prep2_kernel(const float* __restrict__ txT,
                                                    float* __restrict__ w) {
    __shared__ float ssum[512];
    __shared__ float smin[512];
    int t = threadIdx.x;
    float per = 0.0f;
    if (t < T) {
        for (int p = 0; p < P; ++p) {
            per += (txT[p * T + t] >= 0.0f) ? 1.0f : 0.0f;  // coalesced, L2-hot
        }
    }
    ssum[t] = (t < T) ? per : 0.0f;
    smin[t] = (t < T) ? per : 1e30f;
    __syncthreads();
    for (int s = 256; s > 0; s >>= 1) {
        if (t < s) {
            ssum[t] += ssum[t + s];
            smin[t] = fminf(smin[t], smin[t + s]);
        }
        __syncthreads();
    }
    if (t < T) {
        float total   = ssum[0];
        float per_min = smin[0];
        float wmax = sqrtf(total / per_min);     // max of sqrt(total/per) is at per_min
        w[t] = sqrtf(total / per) / wmax;
    }
}

__global__ __launch_bounds__(512) void cost_kernel(const float* __restrict__ logits,
                                                   const float* __restrict__ curves,
                                                   const float* __restrict__ targets,
                                                   const float* __restrict__ ws,
                                                   float* __restrict__ out) {
    const float* lamT = ws;
    const float* txT  = ws + PT;
    const float* tyT  = ws + 2 * PT;
    const float* wv   = ws + 3 * PT;

    int t   = threadIdx.x;
    int bn0 = blockIdx.x * BNB;

    // Per-bn data: wave-uniform (same for every thread in block) -> scalar regs.
    float a0[BNB], a1[BNB], a2[BNB], a3[BNB];
    float b0[BNB], b1[BNB], b2[BNB], b3[BNB];
    float o1v[BNB], o3v[BNB];
    float p0[BNB], p1[BNB], p2[BNB];
#pragma unroll
    for (int j = 0; j < BNB; ++j) {
        const float* ob = curves + (size_t)(bn0 + j) * 8;
        float o0 = ob[0], o1 = ob[1], o2 = ob[2], o3 = ob[3];
        float o4 = ob[4], o5 = ob[5], o6 = ob[6], o7 = ob[7];
        a3[j] = o4; a2[j] = o5; a1[j] = o3 - o4 - o5 - o2; a0[j] = o2;
        b3[j] = o6; b2[j] = o7; b1[j] = o1 - o6 - o7 - o0; b0[j] = o0;
        o1v[j] = o1; o3v[j] = o3;
        const float* lg = logits + (size_t)(bn0 + j) * NCLS;
        float l0 = lg[0], l1 = lg[1], l2 = lg[2];
        float m  = fmaxf(l0, fmaxf(l1, l2));
        float e0 = expf(l0 - m), e1 = expf(l1 - m), e2 = expf(l2 - m);
        float inv = 1.0f / (e0 + e1 + e2);
        p0[j] = e0 * inv; p1[j] = e1 * inv; p2[j] = e2 * inv;
    }

    if (t >= T) return;

    float acc[BNB];
#pragma unroll
    for (int j = 0; j < BNB; ++j) acc[j] = 0.0f;

    for (int p = 0; p < P; ++p) {
        float lam = lamT[p * T + t];   // coalesced across lanes, L2-hot
        float tx  = txT[p * T + t];
        float ty  = tyT[p * T + t];
        bool valid = (tx >= 0.0f);
#pragma unroll
        for (int j = 0; j < BNB; ++j) {
            float ox = fmaf(fmaf(fmaf(a3[j], lam, a2[j]), lam, a1[j]), lam, a0[j]);
            float oy = fmaf(fmaf(fmaf(b3[j], lam, b2[j]), lam, b1[j]), lam, b0[j]);
            float dxv = tx - ox;
            float dyv = ty - oy;
            float s = fmaf(dxv, dxv, dyv * dyv);
            // select (not multiply-by-mask): invalid points must contribute exact 0
            acc[j] += valid ? s : 0.0f;
        }
    }

    const float* row = targets + (size_t)t * TROW;
    int   id = (int)row[0];
    float ly = row[1], uy = row[2], lx = row[3], ux = row[4];
    float wgt = wv[t];

#pragma unroll
    for (int j = 0; j < BNB; ++j) {
        float cl = 0.5f * (fabsf(b0[j]  - ly) + fabsf(a0[j]  - lx));  // ob0, ob2
        float cu = 0.5f * (fabsf(o1v[j] - uy) + fabsf(o3v[j] - ux));  // ob1, ob3
        float prob = (id == 0) ? p0[j] : ((id == 1) ? p1[j] : p2[j]);
        float cp = acc[j] * wgt;
        out[(size_t)(bn0 + j) * T + t] = -prob + cp / 10.0f + cl + cu;
    }
}

extern "C" void kernel_launch(void* const* d_in, const int* in_sizes, int n_in,
                              void* d_out, int out_size, void* d_ws, size_t ws_size,
                              hipStream_t stream) {
    const float* logits  = (const float*)d_in[0];  // (16,128,3)
    const float* curves  = (const float*)d_in[1];  // (16,128,8)
    const float* targets = (const float*)d_in[2];  // (480,149)
    float* out = (float*)d_out;
    float* ws  = (float*)d_ws;

    prep1_kernel<<<PT / 256, 256, 0, stream>>>(targets, ws);
    prep2_kernel<<<1, 512, 0, stream>>>(ws + PT, ws + 3 * PT);
    cost_kernel<<<BN / BNB, 512, 0, stream>>>(logits, curves, targets, ws, out);
}

// Round 2
// 69.538 us; speedup vs baseline: 1.2511x; 1.2511x over previous
//
#include <hip/hip_runtime.h>
#include <math.h>

#define BS   16
#define NQ   128
#define NCLS 3
#define T    480
#define P    72
#define BN   (BS * NQ)      // 2048
#define TROW (5 + 2 * P)    // 149
#define BNB  4              // bn per block in cost kernel

// ws layout (bytes):
//   MD  double[16][T] @ 0      (61440)
//     rows 0..6  : m_j  = sum_valid lam^j            (j=0..6)
//     rows 7..10 : sx_k = -2 * sum_valid tx*lam^k    (k=0..3)
//     rows 11..14: sy_k = -2 * sum_valid ty*lam^k    (k=0..3)
//     row  15    : Q    = sum_valid (tx^2 + ty^2)
//   EF  float[6][T]   @ 61440  (11520): ly, uy, lx, ux, per, id
//   BD  double[BN][8] @ 72960  (131072): P0..P6, pad   (quadratic-form coeffs)
//   BF  float[BN][16] @ 204032 (131072): a0..a3, b0..b3, o1, o3, p0, p1, p2
#define MD_OFF_B 0
#define EF_OFF_B 61440
#define BD_OFF_B 72960
#define BF_OFF_B 204032

// One block (1 wave) per target t: coalesced row reads, fp64 moment
// accumulation, wave butterfly reduction.
__global__ __launch_bounds__(64) void moments_kernel(const float* __restrict__ targets,
                                                     double* __restrict__ MD,
                                                     float* __restrict__ EF) {
    int t    = blockIdx.x;
    int lane = threadIdx.x;
    const float* row = targets + (size_t)t * TROW;
    float ly = row[1], uy = row[2], lx = row[3], ux = row[4];
    float dx = ux - lx, dy = uy - ly;
    float nrm = sqrtf(dx * dx + dy * dy);

    double v[17];
#pragma unroll
    for (int i = 0; i < 17; ++i) v[i] = 0.0;

    for (int p = lane; p < P; p += 64) {
        float tx = row[5 + p];          // coalesced across lanes
        float ty = row[5 + P + p];
        if (tx >= 0.0f) {
            float lamf = dx * (tx - lx) + dy * (ty - ly);
            lamf = lamf / nrm / nrm;    // match reference: dot/nrm/nrm
            double L   = (double)lamf;
            double txd = (double)tx, tyd = (double)ty;
            double lp = 1.0;
#pragma unroll
            for (int j = 0; j < 7; ++j) {
                v[j] += lp;
                if (j < 4) {
                    v[7 + j]  += txd * lp;
                    v[11 + j] += tyd * lp;
                }
                lp *= L;
            }
            v[15] += txd * txd + tyd * tyd;
            v[16] += 1.0;               // per-target valid count
        }
    }

    // 64-lane butterfly reduction of 17 doubles
#pragma unroll
    for (int off = 32; off > 0; off >>= 1) {
#pragma unroll
        for (int i = 0; i < 17; ++i) v[i] += __shfl_down(v[i], off);
    }

    if (lane == 0) {
#pragma unroll
        for (int j = 0; j < 7; ++j) MD[j * T + t] = v[j];
#pragma unroll
        for (int k = 0; k < 4; ++k) {
            MD[(7 + k) * T + t]  = -2.0 * v[7 + k];
            MD[(11 + k) * T + t] = -2.0 * v[11 + k];
        }
        MD[15 * T + t] = v[15];
        EF[0 * T + t] = ly;
        EF[1 * T + t] = uy;
        EF[2 * T + t] = lx;
        EF[3 * T + t] = ux;
        EF[4 * T + t] = (float)v[16];
        EF[5 * T + t] = row[0];         // class id
    }
}

// Per-bn: softmax probs, poly coefficients, quadratic-form P_j in fp64.
__global__ __launch_bounds__(256) void bnprep_kernel(const float* __restrict__ logits,
                                                     const float* __restrict__ curves,
                                                     double* __restrict__ BD,
                                                     float* __restrict__ BF) {
    int bn = blockIdx.x * 256 + threadIdx.x;   // exactly BN
    const float* ob = curves + (size_t)bn * 8;
    float o0 = ob[0], o1 = ob[1], o2 = ob[2], o3 = ob[3];
    float o4 = ob[4], o5 = ob[5], o6 = ob[6], o7 = ob[7];
    float a0 = o2, a1 = o3 - o4 - o5 - o2, a2 = o5, a3 = o4;
    float b0 = o0, b1 = o1 - o6 - o7 - o0, b2 = o7, b3 = o6;

    double A0 = a0, A1 = a1, A2 = a2, A3 = a3;
    double B0 = b0, B1 = b1, B2 = b2, B3 = b3;
    double* Pd = BD + (size_t)bn * 8;
    Pd[0] = A0 * A0 + B0 * B0;
    Pd[1] = 2.0 * (A0 * A1 + B0 * B1);
    Pd[2] = 2.0 * (A0 * A2 + B0 * B2) + A1 * A1 + B1 * B1;
    Pd[3] = 2.0 * (A0 * A3 + A1 * A2 + B0 * B3 + B1 * B2);
    Pd[4] = 2.0 * (A1 * A3 + B1 * B3) + A2 * A2 + B2 * B2;
    Pd[5] = 2.0 * (A2 * A3 + B2 * B3);
    Pd[6] = A3 * A3 + B3 * B3;
    Pd[7] = 0.0;

    const float* lg = logits + (size_t)bn * NCLS;
    float l0 = lg[0], l1 = lg[1], l2 = lg[2];
    float mx = fmaxf(l0, fmaxf(l1, l2));
    float e0 = expf(l0 - mx), e1 = expf(l1 - mx), e2 = expf(l2 - mx);
    float inv = 1.0f / (e0 + e1 + e2);

    float* fb = BF + (size_t)bn * 16;
    fb[0] = a0; fb[1] = a1; fb[2] = a2; fb[3] = a3;
    fb[4] = b0; fb[5] = b1; fb[6] = b2; fb[7] = b3;
    fb[8] = o1; fb[9] = o3;
    fb[10] = e0 * inv; fb[11] = e1 * inv; fb[12] = e2 * inv;
    fb[13] = 0.0f; fb[14] = 0.0f; fb[15] = 0.0f;
}

// thread = t, block = BNB bn's. 16-term fp64 dot per (bn,t).
__global__ __launch_bounds__(512) void cost_kernel(const double* __restrict__ MD,
                                                   const float* __restrict__ EF,
                                                   const double* __restrict__ BD,
                                                   const float* __restrict__ BF,
                                                   float* __restrict__ out) {
    __shared__ float smin[512];
    int t   = threadIdx.x;
    int bn0 = blockIdx.x * BNB;

    // per_min via block reduction (block covers all 480 t, so this is global).
    // w[t] = sqrt(total/per)/max(sqrt(total/per)) = sqrt(per_min/per)  (total cancels)
    float per = (t < T) ? EF[4 * T + t] : 1e30f;
    smin[t] = per;
    __syncthreads();
    for (int s = 256; s > 0; s >>= 1) {
        if (t < s) smin[t] = fminf(smin[t], smin[t + s]);
        __syncthreads();
    }
    float per_min = smin[0];

    if (t >= T) return;
    float w = sqrtf(per_min / per);

    double m[16];
#pragma unroll
    for (int r = 0; r < 16; ++r) m[r] = MD[r * T + t];   // coalesced
    float ly = EF[0 * T + t], uy = EF[1 * T + t];
    float lx = EF[2 * T + t], ux = EF[3 * T + t];
    int   id = (int)EF[5 * T + t];

#pragma unroll
    for (int j = 0; j < BNB; ++j) {
        const double* Pd = BD + (size_t)(bn0 + j) * 8;   // uniform -> s_load
        const float*  fb = BF + (size_t)(bn0 + j) * 16;  // uniform -> s_load
        double acc = m[15];
        acc += Pd[0] * m[0] + Pd[1] * m[1] + Pd[2] * m[2] + Pd[3] * m[3]
             + Pd[4] * m[4] + Pd[5] * m[5] + Pd[6] * m[6];
        acc += (double)fb[0] * m[7]  + (double)fb[1] * m[8]
             + (double)fb[2] * m[9]  + (double)fb[3] * m[10];
        acc += (double)fb[4] * m[11] + (double)fb[5] * m[12]
             + (double)fb[6] * m[13] + (double)fb[7] * m[14];
        float cp = (float)acc * w * 0.1f;
        float cl = 0.5f * (fabsf(fb[4] - ly) + fabsf(fb[0] - lx));   // |ob0-ly|+|ob2-lx|
        float cu = 0.5f * (fabsf(fb[8] - uy) + fabsf(fb[9] - ux));   // |ob1-uy|+|ob3-ux|
        float prob = (id == 0) ? fb[10] : ((id == 1) ? fb[11] : fb[12]);
        out[(size_t)(bn0 + j) * T + t] = -prob + cp + cl + cu;       // coalesced
    }
}

extern "C" void kernel_launch(void* const* d_in, const int* in_sizes, int n_in,
                              void* d_out, int out_size, void* d_ws, size_t ws_size,
                              hipStream_t stream) {
    const float* logits  = (const float*)d_in[0];  // (16,128,3)
    const float* curves  = (const float*)d_in[1];  // (16,128,8)
    const float* targets = (const float*)d_in[2];  // (480,149)
    float* out = (float*)d_out;
    char*  ws  = (char*)d_ws;

    double* MD = (double*)(ws + MD_OFF_B);
    float*  EF = (float*) (ws + EF_OFF_B);
    double* BD = (double*)(ws + BD_OFF_B);
    float*  BF = (float*) (ws + BF_OFF_B);

    moments_kernel<<<T, 64, 0, stream>>>(targets, MD, EF);
    bnprep_kernel<<<BN / 256, 256, 0, stream>>>(logits, curves, BD, BF);
    cost_kernel<<<BN / BNB, 512, 0, stream>>>(MD, EF, BD, BF, out);
}

// Round 3
// 67.101 us; speedup vs baseline: 1.2966x; 1.0363x over previous
//
#include <hip/hip_runtime.h>
#include <math.h>

#define BS   16
#define NQ   128
#define NCLS 3
#define T    480
#define P    72
#define BN   (BS * NQ)      // 2048
#define TROW (5 + 2 * P)    // 149
#define BNB  4              // bn per block in cost kernel

// ws layout (bytes):
//   MD  double[16][T] @ 0      (61440)
//     rows 0..6  : m_j  = sum_valid lam^j            (j=0..6)
//     rows 7..10 : sx_k = -2 * sum_valid tx*lam^k    (k=0..3)
//     rows 11..14: sy_k = -2 * sum_valid ty*lam^k    (k=0..3)
//     row  15    : Q    = sum_valid (tx^2 + ty^2)
//   EF  float[6][T]   @ 61440  (11520): ly, uy, lx, ux, per, id
#define MD_OFF_B 0
#define EF_OFF_B 61440

// One block (1 wave) per target t: coalesced row reads, fp64 moment
// accumulation, wave butterfly reduction.
__global__ __launch_bounds__(64) void moments_kernel(const float* __restrict__ targets,
                                                     double* __restrict__ MD,
                                                     float* __restrict__ EF) {
    int t    = blockIdx.x;
    int lane = threadIdx.x;
    const float* row = targets + (size_t)t * TROW;
    float ly = row[1], uy = row[2], lx = row[3], ux = row[4];
    float dx = ux - lx, dy = uy - ly;
    float nrm = sqrtf(dx * dx + dy * dy);

    double v[17];
#pragma unroll
    for (int i = 0; i < 17; ++i) v[i] = 0.0;

    for (int p = lane; p < P; p += 64) {
        float tx = row[5 + p];          // coalesced across lanes
        float ty = row[5 + P + p];
        if (tx >= 0.0f) {
            float lamf = dx * (tx - lx) + dy * (ty - ly);
            lamf = lamf / nrm / nrm;    // match reference: dot/nrm/nrm
            double L   = (double)lamf;
            double txd = (double)tx, tyd = (double)ty;
            double lp = 1.0;
#pragma unroll
            for (int j = 0; j < 7; ++j) {
                v[j] += lp;
                if (j < 4) {
                    v[7 + j]  += txd * lp;
                    v[11 + j] += tyd * lp;
                }
                lp *= L;
            }
            v[15] += txd * txd + tyd * tyd;
            v[16] += 1.0;               // per-target valid count
        }
    }

    // 64-lane butterfly reduction of 17 doubles
#pragma unroll
    for (int off = 32; off > 0; off >>= 1) {
#pragma unroll
        for (int i = 0; i < 17; ++i) v[i] += __shfl_down(v[i], off);
    }

    if (lane == 0) {
#pragma unroll
        for (int j = 0; j < 7; ++j) MD[j * T + t] = v[j];
#pragma unroll
        for (int k = 0; k < 4; ++k) {
            MD[(7 + k) * T + t]  = -2.0 * v[7 + k];
            MD[(11 + k) * T + t] = -2.0 * v[11 + k];
        }
        MD[15 * T + t] = v[15];
        EF[0 * T + t] = ly;
        EF[1 * T + t] = uy;
        EF[2 * T + t] = lx;
        EF[3 * T + t] = ux;
        EF[4 * T + t] = (float)v[16];
        EF[5 * T + t] = row[0];         // class id
    }
}

// thread = t, block = BNB bn's. Per-bn prep (coeffs + softmax) inlined;
// quadratic-form terms folded directly into the 16-term fp64 dot.
__global__ __launch_bounds__(512) void cost_kernel(const float* __restrict__ logits,
                                                   const float* __restrict__ curves,
                                                   const double* __restrict__ MD,
                                                   const float* __restrict__ EF,
                                                   float* __restrict__ out) {
    __shared__ float wavemin[8];
    int t    = threadIdx.x;
    int bn0  = blockIdx.x * BNB;
    int lane = t & 63;
    int wid  = t >> 6;

    // per_min across all 480 t (block covers all t, so this is global).
    // w[t] = sqrt(total/per)/max(sqrt(total/per)) = sqrt(per_min/per)
    float per = (t < T) ? EF[4 * T + t] : 1e30f;
    float pm = per;
#pragma unroll
    for (int off = 32; off > 0; off >>= 1) pm = fminf(pm, __shfl_xor(pm, off));
    if (lane == 0) wavemin[wid] = pm;
    __syncthreads();
    float per_min = wavemin[0];
#pragma unroll
    for (int i = 1; i < 8; ++i) per_min = fminf(per_min, wavemin[i]);

    if (t >= T) return;
    float w = sqrtf(per_min / per);

    double m[16];
#pragma unroll
    for (int r = 0; r < 16; ++r) m[r] = MD[r * T + t];   // coalesced
    float ly = EF[0 * T + t], uy = EF[1 * T + t];
    float lx = EF[2 * T + t], ux = EF[3 * T + t];
    int   id = (int)EF[5 * T + t];

#pragma unroll
    for (int j = 0; j < BNB; ++j) {
        int bn = bn0 + j;
        const float* ob = curves + (size_t)bn * 8;       // uniform -> s_load
        float o0 = ob[0], o1 = ob[1], o2 = ob[2], o3 = ob[3];
        float o4 = ob[4], o5 = ob[5], o6 = ob[6], o7 = ob[7];
        float a0 = o2, a1 = o3 - o4 - o5 - o2, a2 = o5, a3 = o4;
        float b0 = o0, b1 = o1 - o6 - o7 - o0, b2 = o7, b3 = o6;

        double A0 = a0, A1 = a1, A2 = a2, A3 = a3;
        double B0 = b0, B1 = b1, B2 = b2, B3 = b3;
        double acc = m[15]
            + (A0 * A0 + B0 * B0) * m[0]
            + 2.0 * (A0 * A1 + B0 * B1) * m[1]
            + (2.0 * (A0 * A2 + B0 * B2) + A1 * A1 + B1 * B1) * m[2]
            + 2.0 * (A0 * A3 + A1 * A2 + B0 * B3 + B1 * B2) * m[3]
            + (2.0 * (A1 * A3 + B1 * B3) + A2 * A2 + B2 * B2) * m[4]
            + 2.0 * (A2 * A3 + B2 * B3) * m[5]
            + (A3 * A3 + B3 * B3) * m[6]
            + A0 * m[7]  + A1 * m[8]  + A2 * m[9]  + A3 * m[10]
            + B0 * m[11] + B1 * m[12] + B2 * m[13] + B3 * m[14];

        const float* lg = logits + (size_t)bn * NCLS;    // uniform -> s_load
        float l0 = lg[0], l1 = lg[1], l2 = lg[2];
        float mx = fmaxf(l0, fmaxf(l1, l2));
        float e0 = __expf(l0 - mx), e1 = __expf(l1 - mx), e2 = __expf(l2 - mx);
        float inv = 1.0f / (e0 + e1 + e2);
        float prob = (id == 0) ? e0 * inv : ((id == 1) ? e1 * inv : e2 * inv);

        float cp = (float)acc * w * 0.1f;
        float cl = 0.5f * (fabsf(b0 - ly) + fabsf(a0 - lx));   // |ob0-ly|+|ob2-lx|
        float cu = 0.5f * (fabsf(o1 - uy) + fabsf(o3 - ux));   // |ob1-uy|+|ob3-ux|
        out[(size_t)bn * T + t] = -prob + cp + cl + cu;        // coalesced
    }
}

extern "C" void kernel_launch(void* const* d_in, const int* in_sizes, int n_in,
                              void* d_out, int out_size, void* d_ws, size_t ws_size,
                              hipStream_t stream) {
    const float* logits  = (const float*)d_in[0];  // (16,128,3)
    const float* curves  = (const float*)d_in[1];  // (16,128,8)
    const float* targets = (const float*)d_in[2];  // (480,149)
    float* out = (float*)d_out;
    char*  ws  = (char*)d_ws;

    double* MD = (double*)(ws + MD_OFF_B);
    float*  EF = (float*) (ws + EF_OFF_B);

    moments_kernel<<<T, 64, 0, stream>>>(targets, MD, EF);
    cost_kernel<<<BN / BNB, 512, 0, stream>>>(logits, curves, MD, EF, out);
}